// Round 4
// baseline (92.469 us; speedup 1.0000x reference)
//
#include <hip/hip_runtime.h>
#include <stdint.h>

#define B_ 2
#define N_ 16384
#define P_ 1024
#define C_ 256
#define S_ 64
#define CH_ (C_ + 3)   // 259 output channels
#define CAP_ 512       // key-buffer capacity for selection

#define INF_BITS 0x7F800000u

typedef unsigned long long u64;

struct QSmem {
    u64 keys[CAP_];          // 4 KB
    uint32_t hist[4][256];   // 4 KB (per-wave split histograms)
    u64 red[4];
    uint32_t wsum[4];
    int vflag[128];          // validity of n in [0,128) for the fill step
    int cnt;
    int sel;
    uint32_t k;
};

__device__ __forceinline__ u64 umin64(u64 a, u64 b) { return a < b ? a : b; }

// Block-wide (256 threads) min of u64 keys. Contains barriers; call from all threads.
__device__ u64 block_min_u64(u64 v, u64* s_red) {
    int tid = threadIdx.x;
#pragma unroll
    for (int o = 32; o > 0; o >>= 1)
        v = umin64(v, (u64)__shfl_xor(v, o, 64));
    __syncthreads();
    if ((tid & 63) == 0) s_red[tid >> 6] = v;
    __syncthreads();
    u64 r = s_red[0];
#pragma unroll
    for (int w = 1; w < 4; ++w) r = umin64(r, s_red[w]);
    return r;
}

// Exact score computation (bit-identical to reference evaluation order; no FMA).
__device__ __forceinline__ uint32_t score_bits(const float* __restrict__ xb, int n,
                                               float cx, float cy, float cz,
                                               float r0, float r1, float r2,
                                               float r3, float r4, float r5,
                                               float r6, float r7, float r8) {
    float px = xb[n * 3 + 0], py = xb[n * 3 + 1], pz = xb[n * 3 + 2];
    float dx = px - cx, dy = py - cy, dz = pz - cz;
    float xr = __fadd_rn(__fadd_rn(__fmul_rn(dx, r0), __fmul_rn(dy, r1)), __fmul_rn(dz, r2));
    float yr = __fadd_rn(__fadd_rn(__fmul_rn(dx, r3), __fmul_rn(dy, r4)), __fmul_rn(dz, r5));
    float zr = __fadd_rn(__fadd_rn(__fmul_rn(dx, r6), __fmul_rn(dy, r7)), __fmul_rn(dz, r8));
    float rad2 = __fadd_rn(__fmul_rn(yr, yr), __fmul_rn(zr, zr));
    float radial = __fsqrt_rn(fmaxf(rad2, 0.0f));
    uint32_t sb = INF_BITS;
    if (radial <= 0.05f && xr >= -0.02f && xr <= 0.04f)
        sb = __float_as_uint(__fadd_rn(radial, __fmul_rn(1e-3f, fabsf(xr))));
    return sb;
}

// ---------------- fused: transpose tiles (odd blocks) + cylinder query (even blocks) ----------------
__global__ __launch_bounds__(256) void tq_kernel(const float* __restrict__ feat,
                                                 float* __restrict__ featT,
                                                 const float* __restrict__ xyz,
                                                 const float* __restrict__ new_xyz,
                                                 const float* __restrict__ rot,
                                                 int* __restrict__ idx_out, int useT) {
    __shared__ __align__(16) char smem[64 * 65 * 4];  // 16640 B (union of both paths)
    static_assert(sizeof(QSmem) <= 64 * 65 * 4, "QSmem too big");
    const int tid = threadIdx.x;

    if (blockIdx.x & 1) {
        // ======== transpose path: (B,C,N) -> (B,N,C), one 64x64 tile ========
        if (!useT) return;
        float(*tile)[65] = (float(*)[65])smem;
        int t = blockIdx.x >> 1;
        int b = t >> 10;
        int rem = t & 1023;
        int cblk = rem >> 8;   // 0..3
        int nblk = rem & 255;  // 0..255
        for (int i = tid; i < 1024; i += 256) {
            int cy = i >> 4, nx4 = (i & 15) * 4;
            float4 v = *(const float4*)&feat[((size_t)(b * C_ + cblk * 64 + cy)) * N_ +
                                             nblk * 64 + nx4];
            tile[cy][nx4 + 0] = v.x;
            tile[cy][nx4 + 1] = v.y;
            tile[cy][nx4 + 2] = v.z;
            tile[cy][nx4 + 3] = v.w;
        }
        __syncthreads();
        for (int i = tid; i < 1024; i += 256) {
            int ny = i >> 4, cx4 = (i & 15) * 4;
            float4 v;
            v.x = tile[cx4 + 0][ny];
            v.y = tile[cx4 + 1][ny];
            v.z = tile[cx4 + 2][ny];
            v.w = tile[cx4 + 3][ny];
            *(float4*)&featT[((size_t)(b * N_ + nblk * 64 + ny)) * C_ + cblk * 64 + cx4] = v;
        }
        return;
    }

    // ======== query path ========
    QSmem& qs = *(QSmem*)smem;
    const int lane = tid & 63;
    const int wid = tid >> 6;
    const int bp = blockIdx.x >> 1;  // b*P + p
    const int b = bp >> 10;

    if (tid == 0) qs.cnt = 0;

    const float cx = new_xyz[bp * 3 + 0];
    const float cy = new_xyz[bp * 3 + 1];
    const float cz = new_xyz[bp * 3 + 2];
    const float r0 = rot[bp * 9 + 0], r1 = rot[bp * 9 + 1], r2 = rot[bp * 9 + 2];
    const float r3 = rot[bp * 9 + 3], r4 = rot[bp * 9 + 4], r5 = rot[bp * 9 + 5];
    const float r6 = rot[bp * 9 + 6], r7 = rot[bp * 9 + 7], r8 = rot[bp * 9 + 8];

    __syncthreads();  // qs.cnt initialized

    const float* xb = xyz + (size_t)b * N_ * 3;
    const float4* xb4 = (const float4*)xb;

    // Main pass: 4 points per thread-iteration via 3x dwordx4; wave-aggregated compaction.
    for (int it = 0; it < N_ / 1024; ++it) {
        int t4 = it * 256 + tid;
        float4 A = xb4[t4 * 3 + 0];
        float4 Bv = xb4[t4 * 3 + 1];
        float4 Cv = xb4[t4 * 3 + 2];
        float px[4] = {A.x, A.w, Bv.z, Cv.y};
        float py[4] = {A.y, Bv.x, Bv.w, Cv.z};
        float pz[4] = {A.z, Bv.y, Cv.x, Cv.w};
        int n0 = t4 * 4;
        uint32_t sb[4];
#pragma unroll
        for (int j = 0; j < 4; ++j) {
            float dx = px[j] - cx, dy = py[j] - cy, dz = pz[j] - cz;
            float xr = __fadd_rn(__fadd_rn(__fmul_rn(dx, r0), __fmul_rn(dy, r1)), __fmul_rn(dz, r2));
            float yr = __fadd_rn(__fadd_rn(__fmul_rn(dx, r3), __fmul_rn(dy, r4)), __fmul_rn(dz, r5));
            float zr = __fadd_rn(__fadd_rn(__fmul_rn(dx, r6), __fmul_rn(dy, r7)), __fmul_rn(dz, r8));
            float rad2 = __fadd_rn(__fmul_rn(yr, yr), __fmul_rn(zr, zr));
            float radial = __fsqrt_rn(fmaxf(rad2, 0.0f));
            float score = __fadd_rn(radial, __fmul_rn(1e-3f, fabsf(xr)));
            bool valid = (radial <= 0.05f) && (xr >= -0.02f) && (xr <= 0.04f);
            sb[j] = valid ? __float_as_uint(score) : INF_BITS;
        }
        if (n0 < 128) {
#pragma unroll
            for (int j = 0; j < 4; ++j) qs.vflag[n0 + j] = (sb[j] != INF_BITS) ? 1 : 0;
        }
        uint32_t mn = min(min(sb[0], sb[1]), min(sb[2], sb[3]));
        if (__any(mn != INF_BITS)) {
#pragma unroll
            for (int j = 0; j < 4; ++j) {
                u64 m = __ballot(sb[j] != INF_BITS);
                if (m) {
                    int leader = __builtin_ctzll(m);
                    int cnt = __popcll(m);
                    int base = 0;
                    if (lane == leader) base = atomicAdd(&qs.cnt, cnt);
                    base = __shfl(base, leader, 64);
                    if (sb[j] != INF_BITS) {
                        int pos = base + __popcll(m & ((1ull << lane) - 1ull));
                        if (pos < CAP_) qs.keys[pos] = ((u64)sb[j] << 32) | (unsigned)(n0 + j);
                    }
                }
            }
        }
    }
    __syncthreads();
    const int v = qs.cnt;
    int* out = idx_out + bp * S_;

    if (v == 0) {
        // rare: no point in cylinder -> every slot = argmin d2 (first occurrence)
        u64 fb = ~0ull;
        for (int n = tid; n < N_; n += 256) {
            float px = xb[n * 3 + 0], py = xb[n * 3 + 1], pz = xb[n * 3 + 2];
            float dx = px - cx, dy = py - cy, dz = pz - cz;
            float d2 = __fadd_rn(__fadd_rn(__fmul_rn(dx, dx), __fmul_rn(dy, dy)),
                                 __fmul_rn(dz, dz));
            fb = umin64(fb, ((u64)__float_as_uint(d2) << 32) | (unsigned)n);
        }
        u64 m = block_min_u64(fb, qs.red);
        if (tid < S_) out[tid] = (int)(unsigned)(m & 0xFFFFFFFFu);
        return;
    }

    if (v <= 64) {
        // pad to 64 with unique huge keys
        if (tid >= v && tid < 64)
            qs.keys[tid] = 0xFFFFFFFF00000000ull | (unsigned)(0x10000 + tid);
        __syncthreads();
        // rank sort (keys unique: idx in low bits)
        u64 key = 0;
        int rank = 0;
        if (tid < 64) {
            key = qs.keys[tid];
            for (int o = 0; o < 64; ++o) rank += (qs.keys[o] < key) ? 1 : 0;
        }
        __syncthreads();
        if (tid < 64) qs.keys[rank] = key;
        __syncthreads();
        // fill remaining slots with smallest-index invalid points (ascending).
        // v <= 63 when needed>0, so n in [0,128) contains >= 65 invalid points.
        const int needed = 64 - v;
        if (tid < 64 && needed > 0) {
            bool inv0 = (qs.vflag[tid] == 0);
            u64 m0 = __ballot(inv0);
            int before0 = __popcll(m0 & ((1ull << tid) - 1ull));
            if (inv0 && before0 < needed) qs.keys[v + before0] = (unsigned)tid;
            int c0 = __popcll(m0);
            if (c0 < needed) {
                bool inv1 = (qs.vflag[64 + tid] == 0);
                u64 m1 = __ballot(inv1);
                int b1 = c0 + __popcll(m1 & ((1ull << tid) - 1ull));
                if (inv1 && b1 < needed) qs.keys[v + b1] = (unsigned)(64 + tid);
            }
        }
        __syncthreads();
        if (tid < S_) out[tid] = (int)(unsigned)(qs.keys[tid] & 0xFFFFFFFFu);
        return;
    }

    if (v <= CAP_) {
        // all valid keys already compacted; rank-sort, emit ranks < 64
        for (int i = tid; i < v; i += 256) {
            u64 key = qs.keys[i];
            int rank = 0;
            for (int j = 0; j < v; ++j) rank += (qs.keys[j] < key) ? 1 : 0;
            if (rank < 64) out[rank] = (int)(unsigned)(key & 0xFFFFFFFFu);
        }
        return;
    }

    // ---- rare: v > CAP_. 4-pass radix select of 64th-smallest score (recompute). ----
    uint32_t prefix = 0, mask = 0, kk = 64;
    for (int pass = 0; pass < 4; ++pass) {
        const int shift = 24 - 8 * pass;
        __syncthreads();
        qs.hist[0][tid] = 0;
        qs.hist[1][tid] = 0;
        qs.hist[2][tid] = 0;
        qs.hist[3][tid] = 0;
        __syncthreads();
        for (int n = tid; n < N_; n += 256) {
            uint32_t sb = score_bits(xb, n, cx, cy, cz, r0, r1, r2, r3, r4, r5, r6, r7, r8);
            if (sb != INF_BITS && (sb & mask) == prefix)
                atomicAdd(&qs.hist[wid][(sb >> shift) & 255u], 1u);
        }
        __syncthreads();
        uint32_t cnt = qs.hist[0][tid] + qs.hist[1][tid] + qs.hist[2][tid] + qs.hist[3][tid];
        uint32_t x = cnt;
#pragma unroll
        for (int o = 1; o < 64; o <<= 1) {
            uint32_t y = __shfl_up(x, o, 64);
            if ((tid & 63) >= o) x += y;
        }
        if ((tid & 63) == 63) qs.wsum[wid] = x;
        __syncthreads();
        uint32_t woff = 0;
        for (int w = 0; w < wid; ++w) woff += qs.wsum[w];
        uint32_t incl = x + woff;
        uint32_t excl = incl - cnt;
        if (kk > excl && kk <= incl) {  // exactly one thread
            qs.sel = tid;
            qs.k = kk - excl;
        }
        __syncthreads();
        prefix |= ((uint32_t)qs.sel) << shift;
        mask |= 255u << shift;
        kk = qs.k;
    }
    const uint32_t T = prefix;  // exact 64th-smallest score bits

    __syncthreads();
    if (tid == 0) qs.cnt = 0;
    __syncthreads();
    for (int n = tid; n < N_; n += 256) {
        uint32_t sb = score_bits(xb, n, cx, cy, cz, r0, r1, r2, r3, r4, r5, r6, r7, r8);
        if (sb != INF_BITS && sb <= T) {
            int pos = atomicAdd(&qs.cnt, 1);
            if (pos < CAP_) qs.keys[pos] = ((u64)sb << 32) | (unsigned)n;
        }
    }
    __syncthreads();
    int c = qs.cnt;
    if (c > CAP_) c = CAP_;  // unreachable without >448 exact float ties
    for (int i = tid; i < c; i += 256) {
        u64 key = qs.keys[i];
        int rank = 0;
        for (int j = 0; j < c; ++j) rank += (qs.keys[j] < key) ? 1 : 0;
        if (rank < 64) out[rank] = (int)(unsigned)(key & 0xFFFFFFFFu);
    }
}

// ---------------- grouping: build (B, 3+C, P, S) output ----------------
__global__ __launch_bounds__(256) void group_kernel(const float* __restrict__ featT,
                                                    const float* __restrict__ features,
                                                    const float* __restrict__ xyz,
                                                    const float* __restrict__ new_xyz,
                                                    const float* __restrict__ rot,
                                                    const int* __restrict__ idx,
                                                    float* __restrict__ out, int useT) {
    __shared__ float tile[C_][33];  // 33.8 KB: odd stride -> conflict-free b32 both phases
    __shared__ int s_idx[S_];
    const int tid = threadIdx.x;
    const int bp = blockIdx.x;
    const int b = bp >> 10;
    const int p = bp & 1023;

    if (tid < S_) s_idx[tid] = idx[bp * S_ + tid];
    __syncthreads();

    if (tid < S_) {
        int n = s_idx[tid];
        const float* pt = xyz + ((size_t)b * N_ + n) * 3;
        float dx = pt[0] - new_xyz[bp * 3 + 0];
        float dy = pt[1] - new_xyz[bp * 3 + 1];
        float dz = pt[2] - new_xyz[bp * 3 + 2];
        const float* R = rot + bp * 9;
#pragma unroll
        for (int e = 0; e < 3; ++e) {
            float g = __fadd_rn(__fadd_rn(__fmul_rn(dx, R[0 * 3 + e]), __fmul_rn(dy, R[1 * 3 + e])),
                                __fmul_rn(dz, R[2 * 3 + e]));
            out[(((size_t)b * CH_ + e) * P_ + p) * S_ + tid] = g;
        }
    }

    // two s-halves of 32 samples each
    for (int h = 0; h < 2; ++h) {
        if (h) __syncthreads();  // protect tile reuse
        // Phase A: gather feature rows into tile[c][sl] (1 KB coalesced row per wave-read)
        if (useT) {
            for (int i = tid; i < 32 * C_; i += 256) {
                int sl = i >> 8;  // wave-uniform row
                int n = s_idx[h * 32 + sl];
                tile[tid][sl] = featT[((size_t)b * N_ + n) * C_ + tid];
            }
        } else {
            for (int i = tid; i < 32 * C_; i += 256) {
                int sl = i >> 8;
                int n = s_idx[h * 32 + sl];
                tile[tid][sl] = features[((size_t)b * C_ + tid) * N_ + n];
            }
        }
        __syncthreads();
        // Phase B: float4 output stores, s contiguous (16B/lane; LDS reads <=2-way conflict)
        for (int i = tid; i < C_ * 8; i += 256) {
            int c = i >> 3, s4 = (i & 7) * 4;
            float4 v;
            v.x = tile[c][s4 + 0];
            v.y = tile[c][s4 + 1];
            v.z = tile[c][s4 + 2];
            v.w = tile[c][s4 + 3];
            *(float4*)&out[(((size_t)b * CH_ + 3 + c) * P_ + p) * S_ + h * 32 + s4] = v;
        }
    }
}

extern "C" void kernel_launch(void* const* d_in, const int* in_sizes, int n_in,
                              void* d_out, int out_size, void* d_ws, size_t ws_size,
                              hipStream_t stream) {
    const float* xyz = (const float*)d_in[0];       // (B,N,3)
    const float* new_xyz = (const float*)d_in[1];   // (B,P,3)
    const float* rot = (const float*)d_in[2];       // (B,P,3,3)
    const float* features = (const float*)d_in[3];  // (B,C,N)
    float* out = (float*)d_out;

    const size_t featT_bytes = (size_t)B_ * N_ * C_ * sizeof(float);  // 32 MB
    const size_t idx_bytes = (size_t)B_ * P_ * S_ * sizeof(int);      // 512 KB
    const int useT = (ws_size >= featT_bytes + idx_bytes) ? 1 : 0;

    float* featT = (float*)d_ws;
    int* idx = useT ? (int*)((char*)d_ws + featT_bytes) : (int*)d_ws;

    tq_kernel<<<2 * B_ * P_, 256, 0, stream>>>(features, featT, xyz, new_xyz, rot, idx, useT);
    group_kernel<<<B_ * P_, 256, 0, stream>>>(featT, features, xyz, new_xyz, rot, idx, out, useT);
}

// Round 5
// 84.004 us; speedup vs baseline: 1.1008x; 1.1008x over previous
//
#include <hip/hip_runtime.h>
#include <stdint.h>

#define B_ 2
#define N_ 16384
#define P_ 1024
#define C_ 256
#define S_ 64
#define CH_ (C_ + 3)   // 259 output channels
#define CAP_ 512       // key-buffer capacity for selection

#define INF_BITS 0x7F800000u

typedef unsigned long long u64;

struct QS {
    u64 keys[2][CAP_];      // 8 KB
    uint32_t hist[4][256];  // 4 KB (per-wave split histograms; reused serially per query)
    u64 red[4];
    uint32_t wsum[4];
    int vflag[2][128];      // validity of n in [0,128) per query (for the fill step)
    int cnt[2];
    int sel;
    uint32_t k;
};

__device__ __forceinline__ u64 umin64(u64 a, u64 b) { return a < b ? a : b; }

// Block-wide (256 threads) min of u64 keys. Contains barriers; call uniformly.
__device__ u64 block_min_u64(u64 v, u64* s_red) {
    int tid = threadIdx.x;
#pragma unroll
    for (int o = 32; o > 0; o >>= 1)
        v = umin64(v, (u64)__shfl_xor(v, o, 64));
    __syncthreads();
    if ((tid & 63) == 0) s_red[tid >> 6] = v;
    __syncthreads();
    u64 r = s_red[0];
#pragma unroll
    for (int w = 1; w < 4; ++w) r = umin64(r, s_red[w]);
    return r;
}

// Exact score (bit-identical to reference order; no FMA contraction).
__device__ __forceinline__ uint32_t eval_sb(float px, float py, float pz,
                                            float cx, float cy, float cz,
                                            float r0, float r1, float r2,
                                            float r3, float r4, float r5,
                                            float r6, float r7, float r8) {
    float dx = px - cx, dy = py - cy, dz = pz - cz;
    float xr = __fadd_rn(__fadd_rn(__fmul_rn(dx, r0), __fmul_rn(dy, r1)), __fmul_rn(dz, r2));
    float yr = __fadd_rn(__fadd_rn(__fmul_rn(dx, r3), __fmul_rn(dy, r4)), __fmul_rn(dz, r5));
    float zr = __fadd_rn(__fadd_rn(__fmul_rn(dx, r6), __fmul_rn(dy, r7)), __fmul_rn(dz, r8));
    float rad2 = __fadd_rn(__fmul_rn(yr, yr), __fmul_rn(zr, zr));
    float radial = __fsqrt_rn(fmaxf(rad2, 0.0f));
    bool valid = (radial <= 0.05f) && (xr >= -0.02f) && (xr <= 0.04f);
    float score = __fadd_rn(radial, __fmul_rn(1e-3f, fabsf(xr)));
    return valid ? __float_as_uint(score) : INF_BITS;
}

__device__ __forceinline__ uint32_t score_bits(const float* __restrict__ xb, int n,
                                               float cx, float cy, float cz,
                                               float r0, float r1, float r2,
                                               float r3, float r4, float r5,
                                               float r6, float r7, float r8) {
    return eval_sb(xb[n * 3 + 0], xb[n * 3 + 1], xb[n * 3 + 2],
                   cx, cy, cz, r0, r1, r2, r3, r4, r5, r6, r7, r8);
}

// Wave-aggregated compaction of 4 candidate scores into qs.keys[q].
__device__ __forceinline__ void compact4(QS& qs, int q, uint32_t s0, uint32_t s1,
                                         uint32_t s2, uint32_t s3, int n0, int lane) {
    uint32_t mn = min(min(s0, s1), min(s2, s3));
    if (__any(mn != INF_BITS)) {
        uint32_t sb[4] = {s0, s1, s2, s3};
#pragma unroll
        for (int j = 0; j < 4; ++j) {
            u64 m = __ballot(sb[j] != INF_BITS);
            if (m) {  // wave-uniform
                int leader = __builtin_ctzll(m);
                int cnt = __popcll(m);
                int base = 0;
                if (lane == leader) base = atomicAdd(&qs.cnt[q], cnt);
                base = __shfl(base, leader, 64);
                if (sb[j] != INF_BITS) {
                    int pos = base + __popcll(m & ((1ull << lane) - 1ull));
                    if (pos < CAP_) qs.keys[q][pos] = ((u64)sb[j] << 32) | (unsigned)(n0 + j);
                }
            }
        }
    }
}

// Selection for one query. Branch choice is block-uniform (v in LDS); barriers OK.
__device__ void select_out(QS& qs, int q, const float* __restrict__ xb,
                           float cx, float cy, float cz,
                           float r0, float r1, float r2, float r3, float r4,
                           float r5, float r6, float r7, float r8,
                           int* __restrict__ out) {
    const int tid = threadIdx.x;
    const int wid = tid >> 6;
    const int v = qs.cnt[q];

    if (v == 0) {
        // rare: no point in cylinder -> every slot = argmin d2 (first occurrence)
        u64 fb = ~0ull;
        for (int n = tid; n < N_; n += 256) {
            float px = xb[n * 3 + 0], py = xb[n * 3 + 1], pz = xb[n * 3 + 2];
            float dx = px - cx, dy = py - cy, dz = pz - cz;
            float d2 = __fadd_rn(__fadd_rn(__fmul_rn(dx, dx), __fmul_rn(dy, dy)),
                                 __fmul_rn(dz, dz));
            fb = umin64(fb, ((u64)__float_as_uint(d2) << 32) | (unsigned)n);
        }
        u64 m = block_min_u64(fb, qs.red);
        if (tid < S_) out[tid] = (int)(unsigned)(m & 0xFFFFFFFFu);
    } else if (v <= 64) {
        // pad to 64 with unique huge keys (real idx < 0x4000, pads >= 0x10000)
        if (tid >= v && tid < 64)
            qs.keys[q][tid] = 0xFFFFFFFF00000000ull | (unsigned)(0x10000 + tid);
        __syncthreads();
        u64 key = 0;
        int rank = 0;
        if (tid < 64) {
            key = qs.keys[q][tid];
            for (int o = 0; o < 64; ++o) rank += (qs.keys[q][o] < key) ? 1 : 0;
        }
        __syncthreads();
        if (tid < 64) qs.keys[q][rank] = key;
        __syncthreads();
        // fill remaining slots with smallest-index invalid points (ascending).
        // v <= 63 when needed>0, so n in [0,128) holds >= 65 invalid points.
        const int needed = 64 - v;
        if (tid < 64 && needed > 0) {
            bool inv0 = (qs.vflag[q][tid] == 0);
            u64 m0 = __ballot(inv0);
            int before0 = __popcll(m0 & ((1ull << tid) - 1ull));
            if (inv0 && before0 < needed) qs.keys[q][v + before0] = (unsigned)tid;
            int c0 = __popcll(m0);
            if (c0 < needed) {
                bool inv1 = (qs.vflag[q][64 + tid] == 0);
                u64 m1 = __ballot(inv1);
                int b1 = c0 + __popcll(m1 & ((1ull << tid) - 1ull));
                if (inv1 && b1 < needed) qs.keys[q][v + b1] = (unsigned)(64 + tid);
            }
        }
        __syncthreads();
        if (tid < S_) out[tid] = (int)(unsigned)(qs.keys[q][tid] & 0xFFFFFFFFu);
    } else if (v <= CAP_) {
        // all valid keys already compacted; rank-sort, emit ranks < 64
        for (int i = tid; i < v; i += 256) {
            u64 key = qs.keys[q][i];
            int rank = 0;
            for (int j = 0; j < v; ++j) rank += (qs.keys[q][j] < key) ? 1 : 0;
            if (rank < 64) out[rank] = (int)(unsigned)(key & 0xFFFFFFFFu);
        }
    } else {
        // rare: v > CAP_. 4-pass radix select of 64th-smallest score (recompute).
        uint32_t prefix = 0, mask = 0, kk = 64;
        for (int pass = 0; pass < 4; ++pass) {
            const int shift = 24 - 8 * pass;
            __syncthreads();
            qs.hist[0][tid] = 0;
            qs.hist[1][tid] = 0;
            qs.hist[2][tid] = 0;
            qs.hist[3][tid] = 0;
            __syncthreads();
            for (int n = tid; n < N_; n += 256) {
                uint32_t sb = score_bits(xb, n, cx, cy, cz, r0, r1, r2, r3, r4, r5, r6, r7, r8);
                if (sb != INF_BITS && (sb & mask) == prefix)
                    atomicAdd(&qs.hist[wid][(sb >> shift) & 255u], 1u);
            }
            __syncthreads();
            uint32_t cnt = qs.hist[0][tid] + qs.hist[1][tid] + qs.hist[2][tid] + qs.hist[3][tid];
            uint32_t x = cnt;
#pragma unroll
            for (int o = 1; o < 64; o <<= 1) {
                uint32_t y = __shfl_up(x, o, 64);
                if ((tid & 63) >= o) x += y;
            }
            if ((tid & 63) == 63) qs.wsum[wid] = x;
            __syncthreads();
            uint32_t woff = 0;
            for (int w = 0; w < wid; ++w) woff += qs.wsum[w];
            uint32_t incl = x + woff;
            uint32_t excl = incl - cnt;
            if (kk > excl && kk <= incl) {  // exactly one thread
                qs.sel = tid;
                qs.k = kk - excl;
            }
            __syncthreads();
            prefix |= ((uint32_t)qs.sel) << shift;
            mask |= 255u << shift;
            kk = qs.k;
        }
        const uint32_t T = prefix;  // exact 64th-smallest score bits

        __syncthreads();
        if (tid == 0) qs.cnt[q] = 0;
        __syncthreads();
        for (int n = tid; n < N_; n += 256) {
            uint32_t sb = score_bits(xb, n, cx, cy, cz, r0, r1, r2, r3, r4, r5, r6, r7, r8);
            if (sb != INF_BITS && sb <= T) {
                int pos = atomicAdd(&qs.cnt[q], 1);
                if (pos < CAP_) qs.keys[q][pos] = ((u64)sb << 32) | (unsigned)n;
            }
        }
        __syncthreads();
        int c = qs.cnt[q];
        if (c > CAP_) c = CAP_;  // unreachable without >448 exact float ties
        for (int i = tid; i < c; i += 256) {
            u64 key = qs.keys[q][i];
            int rank = 0;
            for (int j = 0; j < c; ++j) rank += (qs.keys[q][j] < key) ? 1 : 0;
            if (rank < 64) out[rank] = (int)(unsigned)(key & 0xFFFFFFFFu);
        }
    }
}

// ---------------- feature transpose: (B,C,N) -> (B,N,C) ----------------
__global__ __launch_bounds__(256) void transpose_kernel(const float* __restrict__ feat,
                                                        float* __restrict__ featT) {
    int t = blockIdx.x;
    int b = t >> 10;
    int rem = t & 1023;
    int cblk = rem >> 8;   // 0..3
    int nblk = rem & 255;  // 0..255
    __shared__ float tile[64][65];
    int tid = threadIdx.x;
    for (int i = tid; i < 64 * 64; i += 256) {
        int cy = i >> 6, nx = i & 63;
        tile[cy][nx] = feat[((size_t)(b * C_ + cblk * 64 + cy)) * N_ + nblk * 64 + nx];
    }
    __syncthreads();
    for (int i = tid; i < 64 * 64; i += 256) {
        int ny = i >> 6, cx = i & 63;
        featT[((size_t)(b * N_ + nblk * 64 + ny)) * C_ + cblk * 64 + cx] = tile[cx][ny];
    }
}

// ---------------- cylinder query: 2 queries per block ----------------
__global__ __launch_bounds__(256) void query_kernel(const float* __restrict__ xyz,
                                                    const float* __restrict__ new_xyz,
                                                    const float* __restrict__ rot,
                                                    int* __restrict__ idx_out) {
    __shared__ QS qs;
    const int tid = threadIdx.x;
    const int lane = tid & 63;
    const int bp0 = blockIdx.x * 2;  // pairs never straddle a batch (P_ even)
    const int b = bp0 >> 10;

    if (tid == 0) {
        qs.cnt[0] = 0;
        qs.cnt[1] = 0;
    }

    const float c0x = new_xyz[bp0 * 3 + 0], c0y = new_xyz[bp0 * 3 + 1], c0z = new_xyz[bp0 * 3 + 2];
    const float c1x = new_xyz[bp0 * 3 + 3], c1y = new_xyz[bp0 * 3 + 4], c1z = new_xyz[bp0 * 3 + 5];
    const float* R0 = rot + (size_t)bp0 * 9;
    const float q0r0 = R0[0], q0r1 = R0[1], q0r2 = R0[2];
    const float q0r3 = R0[3], q0r4 = R0[4], q0r5 = R0[5];
    const float q0r6 = R0[6], q0r7 = R0[7], q0r8 = R0[8];
    const float q1r0 = R0[9], q1r1 = R0[10], q1r2 = R0[11];
    const float q1r3 = R0[12], q1r4 = R0[13], q1r5 = R0[14];
    const float q1r6 = R0[15], q1r7 = R0[16], q1r8 = R0[17];

    __syncthreads();  // cnt initialized

    const float* xb = xyz + (size_t)b * N_ * 3;
    const float4* xb4 = (const float4*)xb;

    // Main pass: 4 points/thread/iter (3x dwordx4), evaluated against both queries.
    for (int it = 0; it < N_ / 1024; ++it) {
        int t4 = it * 256 + tid;
        float4 A = xb4[t4 * 3 + 0];
        float4 Bv = xb4[t4 * 3 + 1];
        float4 Cv = xb4[t4 * 3 + 2];
        float px0 = A.x, py0 = A.y, pz0 = A.z;
        float px1 = A.w, py1 = Bv.x, pz1 = Bv.y;
        float px2 = Bv.z, py2 = Bv.w, pz2 = Cv.x;
        float px3 = Cv.y, py3 = Cv.z, pz3 = Cv.w;
        int n0 = t4 * 4;

        uint32_t s00 = eval_sb(px0, py0, pz0, c0x, c0y, c0z, q0r0, q0r1, q0r2, q0r3, q0r4, q0r5, q0r6, q0r7, q0r8);
        uint32_t s01 = eval_sb(px1, py1, pz1, c0x, c0y, c0z, q0r0, q0r1, q0r2, q0r3, q0r4, q0r5, q0r6, q0r7, q0r8);
        uint32_t s02 = eval_sb(px2, py2, pz2, c0x, c0y, c0z, q0r0, q0r1, q0r2, q0r3, q0r4, q0r5, q0r6, q0r7, q0r8);
        uint32_t s03 = eval_sb(px3, py3, pz3, c0x, c0y, c0z, q0r0, q0r1, q0r2, q0r3, q0r4, q0r5, q0r6, q0r7, q0r8);
        uint32_t s10 = eval_sb(px0, py0, pz0, c1x, c1y, c1z, q1r0, q1r1, q1r2, q1r3, q1r4, q1r5, q1r6, q1r7, q1r8);
        uint32_t s11 = eval_sb(px1, py1, pz1, c1x, c1y, c1z, q1r0, q1r1, q1r2, q1r3, q1r4, q1r5, q1r6, q1r7, q1r8);
        uint32_t s12 = eval_sb(px2, py2, pz2, c1x, c1y, c1z, q1r0, q1r1, q1r2, q1r3, q1r4, q1r5, q1r6, q1r7, q1r8);
        uint32_t s13 = eval_sb(px3, py3, pz3, c1x, c1y, c1z, q1r0, q1r1, q1r2, q1r3, q1r4, q1r5, q1r6, q1r7, q1r8);

        if (it == 0 && tid < 32) {
            qs.vflag[0][n0 + 0] = (s00 != INF_BITS) ? 1 : 0;
            qs.vflag[0][n0 + 1] = (s01 != INF_BITS) ? 1 : 0;
            qs.vflag[0][n0 + 2] = (s02 != INF_BITS) ? 1 : 0;
            qs.vflag[0][n0 + 3] = (s03 != INF_BITS) ? 1 : 0;
            qs.vflag[1][n0 + 0] = (s10 != INF_BITS) ? 1 : 0;
            qs.vflag[1][n0 + 1] = (s11 != INF_BITS) ? 1 : 0;
            qs.vflag[1][n0 + 2] = (s12 != INF_BITS) ? 1 : 0;
            qs.vflag[1][n0 + 3] = (s13 != INF_BITS) ? 1 : 0;
        }
        compact4(qs, 0, s00, s01, s02, s03, n0, lane);
        compact4(qs, 1, s10, s11, s12, s13, n0, lane);
    }
    __syncthreads();

    select_out(qs, 0, xb, c0x, c0y, c0z, q0r0, q0r1, q0r2, q0r3, q0r4, q0r5, q0r6, q0r7, q0r8,
               idx_out + (size_t)bp0 * S_);
    __syncthreads();  // protect shared hist/red/keys reuse between queries
    select_out(qs, 1, xb, c1x, c1y, c1z, q1r0, q1r1, q1r2, q1r3, q1r4, q1r5, q1r6, q1r7, q1r8,
               idx_out + (size_t)(bp0 + 1) * S_);
}

// ---------------- grouping: build (B, 3+C, P, S) output ----------------
__global__ __launch_bounds__(256) void group_kernel(const float* __restrict__ featT,
                                                    const float* __restrict__ features,
                                                    const float* __restrict__ xyz,
                                                    const float* __restrict__ new_xyz,
                                                    const float* __restrict__ rot,
                                                    const int* __restrict__ idx,
                                                    float* __restrict__ out, int useT) {
    __shared__ float tile[C_][33];  // 33.8 KB: odd stride -> conflict-free b32 both phases
    __shared__ int s_idx[S_];
    const int tid = threadIdx.x;
    const int bp = blockIdx.x;
    const int b = bp >> 10;
    const int p = bp & 1023;

    if (tid < S_) s_idx[tid] = idx[bp * S_ + tid];
    __syncthreads();

    if (tid < S_) {
        int n = s_idx[tid];
        const float* pt = xyz + ((size_t)b * N_ + n) * 3;
        float dx = pt[0] - new_xyz[bp * 3 + 0];
        float dy = pt[1] - new_xyz[bp * 3 + 1];
        float dz = pt[2] - new_xyz[bp * 3 + 2];
        const float* R = rot + bp * 9;
#pragma unroll
        for (int e = 0; e < 3; ++e) {
            float g = __fadd_rn(__fadd_rn(__fmul_rn(dx, R[0 * 3 + e]), __fmul_rn(dy, R[1 * 3 + e])),
                                __fmul_rn(dz, R[2 * 3 + e]));
            out[(((size_t)b * CH_ + e) * P_ + p) * S_ + tid] = g;
        }
    }

    // two s-halves of 32 samples each
    for (int h = 0; h < 2; ++h) {
        if (h) __syncthreads();  // protect tile reuse
        // Phase A: gather feature rows into tile[c][sl] (1 KB coalesced row per wave-read)
        if (useT) {
            for (int i = tid; i < 32 * C_; i += 256) {
                int sl = i >> 8;  // wave-uniform row
                int n = s_idx[h * 32 + sl];
                tile[tid][sl] = featT[((size_t)b * N_ + n) * C_ + tid];
            }
        } else {
            for (int i = tid; i < 32 * C_; i += 256) {
                int sl = i >> 8;
                int n = s_idx[h * 32 + sl];
                tile[tid][sl] = features[((size_t)b * C_ + tid) * N_ + n];
            }
        }
        __syncthreads();
        // Phase B: float4 output stores, s contiguous (16B/lane)
        for (int i = tid; i < C_ * 8; i += 256) {
            int c = i >> 3, s4 = (i & 7) * 4;
            float4 v;
            v.x = tile[c][s4 + 0];
            v.y = tile[c][s4 + 1];
            v.z = tile[c][s4 + 2];
            v.w = tile[c][s4 + 3];
            *(float4*)&out[(((size_t)b * CH_ + 3 + c) * P_ + p) * S_ + h * 32 + s4] = v;
        }
    }
}

extern "C" void kernel_launch(void* const* d_in, const int* in_sizes, int n_in,
                              void* d_out, int out_size, void* d_ws, size_t ws_size,
                              hipStream_t stream) {
    const float* xyz = (const float*)d_in[0];       // (B,N,3)
    const float* new_xyz = (const float*)d_in[1];   // (B,P,3)
    const float* rot = (const float*)d_in[2];       // (B,P,3,3)
    const float* features = (const float*)d_in[3];  // (B,C,N)
    float* out = (float*)d_out;

    const size_t featT_bytes = (size_t)B_ * N_ * C_ * sizeof(float);  // 32 MB
    const size_t idx_bytes = (size_t)B_ * P_ * S_ * sizeof(int);      // 512 KB
    const int useT = (ws_size >= featT_bytes + idx_bytes) ? 1 : 0;

    float* featT = (float*)d_ws;
    int* idx = useT ? (int*)((char*)d_ws + featT_bytes) : (int*)d_ws;

    if (useT) {
        transpose_kernel<<<2048, 256, 0, stream>>>(features, featT);
    }
    query_kernel<<<B_ * P_ / 2, 256, 0, stream>>>(xyz, new_xyz, rot, idx);
    group_kernel<<<B_ * P_, 256, 0, stream>>>(featT, features, xyz, new_xyz, rot, idx, out, useT);
}

// Round 6
// 74.063 us; speedup vs baseline: 1.2485x; 1.1342x over previous
//
#include <hip/hip_runtime.h>
#include <stdint.h>

#define B_ 2
#define N_ 16384
#define P_ 1024
#define C_ 256
#define S_ 64
#define CH_ (C_ + 3)   // 259 output channels
#define CAP_ 512       // key-buffer capacity for selection

#define INF_BITS 0x7F800000u

typedef unsigned long long u64;

struct QS {
    u64 keys[CAP_];         // 4 KB
    uint32_t hist[4][256];  // 4 KB (per-wave split histograms)
    u64 red[4];
    uint32_t wsum[4];
    int vflag[128];         // validity of n in [0,128) (for the fill step)
    int cnt;
    int sel;
    uint32_t k;
};

struct GT {
    float tile[C_][33];     // 33.8 KB: odd stride -> conflict-light in all phases
};

union USmem {
    QS qs;
    GT g;
};

__device__ __forceinline__ u64 umin64(u64 a, u64 b) { return a < b ? a : b; }

// bf16 round-to-nearest-even (values are finite normals here)
__device__ __forceinline__ uint32_t f2bf(float f) {
    uint32_t x = __float_as_uint(f);
    return (x + 0x7fffu + ((x >> 16) & 1u)) >> 16;
}
__device__ __forceinline__ float bf2f(uint32_t u) { return __uint_as_float(u << 16); }

// Block-wide (256 threads) min of u64 keys. Contains barriers; call uniformly.
__device__ u64 block_min_u64(u64 v, u64* s_red) {
    int tid = threadIdx.x;
#pragma unroll
    for (int o = 32; o > 0; o >>= 1)
        v = umin64(v, (u64)__shfl_xor(v, o, 64));
    __syncthreads();
    if ((tid & 63) == 0) s_red[tid >> 6] = v;
    __syncthreads();
    u64 r = s_red[0];
#pragma unroll
    for (int w = 1; w < 4; ++w) r = umin64(r, s_red[w]);
    return r;
}

// Exact score (bit-identical to reference order; no FMA contraction).
__device__ __forceinline__ uint32_t eval_sb(float px, float py, float pz,
                                            float cx, float cy, float cz,
                                            float r0, float r1, float r2,
                                            float r3, float r4, float r5,
                                            float r6, float r7, float r8) {
    float dx = px - cx, dy = py - cy, dz = pz - cz;
    float xr = __fadd_rn(__fadd_rn(__fmul_rn(dx, r0), __fmul_rn(dy, r1)), __fmul_rn(dz, r2));
    float yr = __fadd_rn(__fadd_rn(__fmul_rn(dx, r3), __fmul_rn(dy, r4)), __fmul_rn(dz, r5));
    float zr = __fadd_rn(__fadd_rn(__fmul_rn(dx, r6), __fmul_rn(dy, r7)), __fmul_rn(dz, r8));
    float rad2 = __fadd_rn(__fmul_rn(yr, yr), __fmul_rn(zr, zr));
    float radial = __fsqrt_rn(fmaxf(rad2, 0.0f));
    bool valid = (radial <= 0.05f) && (xr >= -0.02f) && (xr <= 0.04f);
    float score = __fadd_rn(radial, __fmul_rn(1e-3f, fabsf(xr)));
    return valid ? __float_as_uint(score) : INF_BITS;
}

__device__ __forceinline__ uint32_t score_bits(const float* __restrict__ xb, int n,
                                               float cx, float cy, float cz,
                                               float r0, float r1, float r2,
                                               float r3, float r4, float r5,
                                               float r6, float r7, float r8) {
    return eval_sb(xb[n * 3 + 0], xb[n * 3 + 1], xb[n * 3 + 2],
                   cx, cy, cz, r0, r1, r2, r3, r4, r5, r6, r7, r8);
}

// Selection for one query -> writes 64 indices to s_out (LDS).
// Branch choice is block-uniform (v in LDS); barriers OK. No early returns.
__device__ void select_idx(QS& qs, const float* __restrict__ xb,
                           float cx, float cy, float cz,
                           float r0, float r1, float r2, float r3, float r4,
                           float r5, float r6, float r7, float r8,
                           int* s_out) {
    const int tid = threadIdx.x;
    const int wid = tid >> 6;
    const int v = qs.cnt;

    if (v == 0) {
        // rare: no point in cylinder -> every slot = argmin d2 (first occurrence)
        u64 fb = ~0ull;
        for (int n = tid; n < N_; n += 256) {
            float px = xb[n * 3 + 0], py = xb[n * 3 + 1], pz = xb[n * 3 + 2];
            float dx = px - cx, dy = py - cy, dz = pz - cz;
            float d2 = __fadd_rn(__fadd_rn(__fmul_rn(dx, dx), __fmul_rn(dy, dy)),
                                 __fmul_rn(dz, dz));
            fb = umin64(fb, ((u64)__float_as_uint(d2) << 32) | (unsigned)n);
        }
        u64 m = block_min_u64(fb, qs.red);
        if (tid < S_) s_out[tid] = (int)(unsigned)(m & 0xFFFFFFFFu);
    } else if (v <= 64) {
        // pad to 64 with unique huge keys (real idx < 0x4000, pads >= 0x10000)
        if (tid >= v && tid < 64)
            qs.keys[tid] = 0xFFFFFFFF00000000ull | (unsigned)(0x10000 + tid);
        __syncthreads();
        u64 key = 0;
        int rank = 0;
        if (tid < 64) {
            key = qs.keys[tid];
            for (int o = 0; o < 64; ++o) rank += (qs.keys[o] < key) ? 1 : 0;
        }
        __syncthreads();
        if (tid < 64) qs.keys[rank] = key;
        __syncthreads();
        // fill remaining slots with smallest-index invalid points (ascending).
        // v <= 63 when needed>0, so n in [0,128) holds >= 65 invalid points.
        const int needed = 64 - v;
        if (tid < 64 && needed > 0) {
            bool inv0 = (qs.vflag[tid] == 0);
            u64 m0 = __ballot(inv0);
            int before0 = __popcll(m0 & ((1ull << tid) - 1ull));
            if (inv0 && before0 < needed) qs.keys[v + before0] = (unsigned)tid;
            int c0 = __popcll(m0);
            if (c0 < needed) {
                bool inv1 = (qs.vflag[64 + tid] == 0);
                u64 m1 = __ballot(inv1);
                int b1 = c0 + __popcll(m1 & ((1ull << tid) - 1ull));
                if (inv1 && b1 < needed) qs.keys[v + b1] = (unsigned)(64 + tid);
            }
        }
        __syncthreads();
        if (tid < S_) s_out[tid] = (int)(unsigned)(qs.keys[tid] & 0xFFFFFFFFu);
    } else if (v <= CAP_) {
        // all valid keys already compacted; rank-sort, emit ranks < 64
        for (int i = tid; i < v; i += 256) {
            u64 key = qs.keys[i];
            int rank = 0;
            for (int j = 0; j < v; ++j) rank += (qs.keys[j] < key) ? 1 : 0;
            if (rank < 64) s_out[rank] = (int)(unsigned)(key & 0xFFFFFFFFu);
        }
    } else {
        // rare: v > CAP_. 4-pass radix select of 64th-smallest score (recompute).
        uint32_t prefix = 0, mask = 0, kk = 64;
        for (int pass = 0; pass < 4; ++pass) {
            const int shift = 24 - 8 * pass;
            __syncthreads();
            qs.hist[0][tid] = 0;
            qs.hist[1][tid] = 0;
            qs.hist[2][tid] = 0;
            qs.hist[3][tid] = 0;
            __syncthreads();
            for (int n = tid; n < N_; n += 256) {
                uint32_t sb = score_bits(xb, n, cx, cy, cz, r0, r1, r2, r3, r4, r5, r6, r7, r8);
                if (sb != INF_BITS && (sb & mask) == prefix)
                    atomicAdd(&qs.hist[wid][(sb >> shift) & 255u], 1u);
            }
            __syncthreads();
            uint32_t cnt = qs.hist[0][tid] + qs.hist[1][tid] + qs.hist[2][tid] + qs.hist[3][tid];
            uint32_t x = cnt;
#pragma unroll
            for (int o = 1; o < 64; o <<= 1) {
                uint32_t y = __shfl_up(x, o, 64);
                if ((tid & 63) >= o) x += y;
            }
            if ((tid & 63) == 63) qs.wsum[wid] = x;
            __syncthreads();
            uint32_t woff = 0;
            for (int w = 0; w < wid; ++w) woff += qs.wsum[w];
            uint32_t incl = x + woff;
            uint32_t excl = incl - cnt;
            if (kk > excl && kk <= incl) {  // exactly one thread
                qs.sel = tid;
                qs.k = kk - excl;
            }
            __syncthreads();
            prefix |= ((uint32_t)qs.sel) << shift;
            mask |= 255u << shift;
            kk = qs.k;
        }
        const uint32_t T = prefix;  // exact 64th-smallest score bits

        __syncthreads();
        if (tid == 0) qs.cnt = 0;
        __syncthreads();
        for (int n = tid; n < N_; n += 256) {
            uint32_t sb = score_bits(xb, n, cx, cy, cz, r0, r1, r2, r3, r4, r5, r6, r7, r8);
            if (sb != INF_BITS && sb <= T) {
                int pos = atomicAdd(&qs.cnt, 1);
                if (pos < CAP_) qs.keys[pos] = ((u64)sb << 32) | (unsigned)n;
            }
        }
        __syncthreads();
        int c = qs.cnt;
        if (c > CAP_) c = CAP_;  // unreachable without >448 exact float ties
        for (int i = tid; i < c; i += 256) {
            u64 key = qs.keys[i];
            int rank = 0;
            for (int j = 0; j < c; ++j) rank += (qs.keys[j] < key) ? 1 : 0;
            if (rank < 64) s_out[rank] = (int)(unsigned)(key & 0xFFFFFFFFu);
        }
    }
}

// ---------------- feature transpose: (B,C,N) fp32 -> (B,N,C) bf16 ----------------
__global__ __launch_bounds__(256) void transpose_kernel(const float* __restrict__ feat,
                                                        ushort* __restrict__ featT) {
    int t = blockIdx.x;
    int b = t >> 10;
    int rem = t & 1023;
    int cblk = rem >> 8;   // 0..3
    int nblk = rem & 255;  // 0..255
    __shared__ float tile[64][65];
    int tid = threadIdx.x;
    for (int i = tid; i < 64 * 64; i += 256) {
        int cy = i >> 6, nx = i & 63;
        tile[cy][nx] = feat[((size_t)(b * C_ + cblk * 64 + cy)) * N_ + nblk * 64 + nx];
    }
    __syncthreads();
    // write bf16 pairs: 64 rows (ny) x 32 channel-pairs
    for (int i = tid; i < 64 * 32; i += 256) {
        int ny = i >> 5, cp = i & 31;
        uint32_t u0 = f2bf(tile[2 * cp + 0][ny]);
        uint32_t u1 = f2bf(tile[2 * cp + 1][ny]);
        *(uint32_t*)&featT[((size_t)(b * N_ + nblk * 64 + ny)) * C_ + cblk * 64 + 2 * cp] =
            u0 | (u1 << 16);
    }
}

// ---------------- fused: cylinder query + group, one bp per block ----------------
__global__ __launch_bounds__(256) void qg_kernel(const ushort* __restrict__ featT,
                                                 const float* __restrict__ features,
                                                 const float* __restrict__ xyz,
                                                 const float* __restrict__ new_xyz,
                                                 const float* __restrict__ rot,
                                                 float* __restrict__ out, int useT) {
    __shared__ USmem sm;
    __shared__ int s_idx[S_];
    const int tid = threadIdx.x;
    const int lane = tid & 63;
    const int bp = blockIdx.x;
    const int b = bp >> 10;
    const int p = bp & 1023;

    if (tid == 0) sm.qs.cnt = 0;

    const float cx = new_xyz[bp * 3 + 0];
    const float cy = new_xyz[bp * 3 + 1];
    const float cz = new_xyz[bp * 3 + 2];
    const float* R = rot + (size_t)bp * 9;
    const float r0 = R[0], r1 = R[1], r2 = R[2];
    const float r3 = R[3], r4 = R[4], r5 = R[5];
    const float r6 = R[6], r7 = R[7], r8 = R[8];

    __syncthreads();  // cnt initialized

    const float* xb = xyz + (size_t)b * N_ * 3;
    const float4* xb4 = (const float4*)xb;

    // ---- query main pass: 4 points/thread/iter via 3x dwordx4 ----
    for (int it = 0; it < N_ / 1024; ++it) {
        int t4 = it * 256 + tid;
        float4 A = xb4[t4 * 3 + 0];
        float4 Bv = xb4[t4 * 3 + 1];
        float4 Cv = xb4[t4 * 3 + 2];
        int n0 = t4 * 4;

        uint32_t s0 = eval_sb(A.x, A.y, A.z, cx, cy, cz, r0, r1, r2, r3, r4, r5, r6, r7, r8);
        uint32_t s1 = eval_sb(A.w, Bv.x, Bv.y, cx, cy, cz, r0, r1, r2, r3, r4, r5, r6, r7, r8);
        uint32_t s2 = eval_sb(Bv.z, Bv.w, Cv.x, cx, cy, cz, r0, r1, r2, r3, r4, r5, r6, r7, r8);
        uint32_t s3 = eval_sb(Cv.y, Cv.z, Cv.w, cx, cy, cz, r0, r1, r2, r3, r4, r5, r6, r7, r8);

        if (it == 0 && tid < 32) {
            sm.qs.vflag[n0 + 0] = (s0 != INF_BITS) ? 1 : 0;
            sm.qs.vflag[n0 + 1] = (s1 != INF_BITS) ? 1 : 0;
            sm.qs.vflag[n0 + 2] = (s2 != INF_BITS) ? 1 : 0;
            sm.qs.vflag[n0 + 3] = (s3 != INF_BITS) ? 1 : 0;
        }
        uint32_t mn = min(min(s0, s1), min(s2, s3));
        if (__any(mn != INF_BITS)) {
            uint32_t sb[4] = {s0, s1, s2, s3};
#pragma unroll
            for (int j = 0; j < 4; ++j) {
                u64 m = __ballot(sb[j] != INF_BITS);
                if (m) {  // wave-uniform
                    int leader = __builtin_ctzll(m);
                    int cnt = __popcll(m);
                    int base = 0;
                    if (lane == leader) base = atomicAdd(&sm.qs.cnt, cnt);
                    base = __shfl(base, leader, 64);
                    if (sb[j] != INF_BITS) {
                        int pos = base + __popcll(m & ((1ull << lane) - 1ull));
                        if (pos < CAP_) sm.qs.keys[pos] = ((u64)sb[j] << 32) | (unsigned)(n0 + j);
                    }
                }
            }
        }
    }
    __syncthreads();

    // ---- selection -> s_idx (LDS) ----
    select_idx(sm.qs, xb, cx, cy, cz, r0, r1, r2, r3, r4, r5, r6, r7, r8, s_idx);
    __syncthreads();  // s_idx visible; qs no longer read (tile may overwrite union)

    // ---- group: xyz part (3 channels) ----
    if (tid < S_) {
        int n = s_idx[tid];
        const float* pt = xyz + ((size_t)b * N_ + n) * 3;
        float dx = pt[0] - cx;
        float dy = pt[1] - cy;
        float dz = pt[2] - cz;
        // g_e = ((dx*R[0,e] + dy*R[1,e]) + dz*R[2,e]), no FMA
        float g0 = __fadd_rn(__fadd_rn(__fmul_rn(dx, r0), __fmul_rn(dy, r3)), __fmul_rn(dz, r6));
        float g1 = __fadd_rn(__fadd_rn(__fmul_rn(dx, r1), __fmul_rn(dy, r4)), __fmul_rn(dz, r7));
        float g2 = __fadd_rn(__fadd_rn(__fmul_rn(dx, r2), __fmul_rn(dy, r5)), __fmul_rn(dz, r8));
        out[(((size_t)b * CH_ + 0) * P_ + p) * S_ + tid] = g0;
        out[(((size_t)b * CH_ + 1) * P_ + p) * S_ + tid] = g1;
        out[(((size_t)b * CH_ + 2) * P_ + p) * S_ + tid] = g2;
    }

    // ---- group: features, two s-halves of 32 samples each ----
    for (int h = 0; h < 2; ++h) {
        if (h) __syncthreads();  // protect tile reuse
        if (useT) {
            // gather bf16 rows: per iter one uint (2 channels) per thread, 256B/wave coalesced
            for (int i = tid; i < 32 * 128; i += 256) {
                int sl = i >> 7, cp = i & 127;
                int n = s_idx[h * 32 + sl];
                uint32_t v = *(const uint32_t*)&featT[((size_t)b * N_ + n) * C_ + cp * 2];
                sm.g.tile[2 * cp + 0][sl] = bf2f(v & 0xffffu);
                sm.g.tile[2 * cp + 1][sl] = bf2f(v >> 16);
            }
        } else {
            for (int i = tid; i < 32 * C_; i += 256) {
                int sl = i >> 8;  // wave-uniform row
                int n = s_idx[h * 32 + sl];
                sm.g.tile[tid][sl] = features[((size_t)b * C_ + tid) * N_ + n];
            }
        }
        __syncthreads();
        // Phase B: float4 output stores, s contiguous (16B/lane)
        for (int i = tid; i < C_ * 8; i += 256) {
            int c = i >> 3, s4 = (i & 7) * 4;
            float4 v;
            v.x = sm.g.tile[c][s4 + 0];
            v.y = sm.g.tile[c][s4 + 1];
            v.z = sm.g.tile[c][s4 + 2];
            v.w = sm.g.tile[c][s4 + 3];
            *(float4*)&out[(((size_t)b * CH_ + 3 + c) * P_ + p) * S_ + h * 32 + s4] = v;
        }
    }
}

extern "C" void kernel_launch(void* const* d_in, const int* in_sizes, int n_in,
                              void* d_out, int out_size, void* d_ws, size_t ws_size,
                              hipStream_t stream) {
    const float* xyz = (const float*)d_in[0];       // (B,N,3)
    const float* new_xyz = (const float*)d_in[1];   // (B,P,3)
    const float* rot = (const float*)d_in[2];       // (B,P,3,3)
    const float* features = (const float*)d_in[3];  // (B,C,N)
    float* out = (float*)d_out;

    const size_t featT_bytes = (size_t)B_ * N_ * C_ * sizeof(ushort);  // 16.8 MB
    const int useT = (ws_size >= featT_bytes) ? 1 : 0;

    ushort* featT = (ushort*)d_ws;

    if (useT) {
        transpose_kernel<<<2048, 256, 0, stream>>>(features, featT);
    }
    qg_kernel<<<B_ * P_, 256, 0, stream>>>(featT, features, xyz, new_xyz, rot, out, useT);
}

// Round 7
// 65.804 us; speedup vs baseline: 1.4052x; 1.1255x over previous
//
#include <hip/hip_runtime.h>
#include <stdint.h>

#define B_ 2
#define N_ 16384
#define P_ 1024
#define C_ 256
#define S_ 64
#define CH_ (C_ + 3)   // 259 output channels
#define CAP_ 512       // key-buffer capacity for selection

#define INF_BITS 0x7F800000u

typedef unsigned long long u64;

struct QS {
    u64 keys[CAP_];         // 4 KB
    uint32_t hist[4][256];  // 4 KB (per-wave split histograms)
    u64 red[4];
    uint32_t wsum[4];
    int vflag[128];         // validity of n in [0,128) (for the fill step)
    int cnt;
    int sel;
    uint32_t k;
};

struct GT {
    uint32_t tileu[32][130];  // 16.6 KB; [sample][channel-pair], bf16x2 packed
};

union USmem {
    QS qs;
    GT g;
};

__device__ __forceinline__ u64 umin64(u64 a, u64 b) { return a < b ? a : b; }

// bf16 round-to-nearest-even (values are finite normals here)
__device__ __forceinline__ uint32_t f2bf(float f) {
    uint32_t x = __float_as_uint(f);
    return (x + 0x7fffu + ((x >> 16) & 1u)) >> 16;
}
__device__ __forceinline__ float bf2f(uint32_t u) { return __uint_as_float(u << 16); }

// Block-wide (256 threads) min of u64 keys. Contains barriers; call uniformly.
__device__ u64 block_min_u64(u64 v, u64* s_red) {
    int tid = threadIdx.x;
#pragma unroll
    for (int o = 32; o > 0; o >>= 1)
        v = umin64(v, (u64)__shfl_xor(v, o, 64));
    __syncthreads();
    if ((tid & 63) == 0) s_red[tid >> 6] = v;
    __syncthreads();
    u64 r = s_red[0];
#pragma unroll
    for (int w = 1; w < 4; ++w) r = umin64(r, s_red[w]);
    return r;
}

// Exact score (bit-identical to reference order; no FMA contraction).
__device__ __forceinline__ uint32_t eval_sb(float px, float py, float pz,
                                            float cx, float cy, float cz,
                                            float r0, float r1, float r2,
                                            float r3, float r4, float r5,
                                            float r6, float r7, float r8) {
    float dx = px - cx, dy = py - cy, dz = pz - cz;
    float xr = __fadd_rn(__fadd_rn(__fmul_rn(dx, r0), __fmul_rn(dy, r1)), __fmul_rn(dz, r2));
    float yr = __fadd_rn(__fadd_rn(__fmul_rn(dx, r3), __fmul_rn(dy, r4)), __fmul_rn(dz, r5));
    float zr = __fadd_rn(__fadd_rn(__fmul_rn(dx, r6), __fmul_rn(dy, r7)), __fmul_rn(dz, r8));
    float rad2 = __fadd_rn(__fmul_rn(yr, yr), __fmul_rn(zr, zr));
    float radial = __fsqrt_rn(fmaxf(rad2, 0.0f));
    bool valid = (radial <= 0.05f) && (xr >= -0.02f) && (xr <= 0.04f);
    float score = __fadd_rn(radial, __fmul_rn(1e-3f, fabsf(xr)));
    return valid ? __float_as_uint(score) : INF_BITS;
}

__device__ __forceinline__ uint32_t score_bits(const float* __restrict__ xb, int n,
                                               float cx, float cy, float cz,
                                               float r0, float r1, float r2,
                                               float r3, float r4, float r5,
                                               float r6, float r7, float r8) {
    return eval_sb(xb[n * 3 + 0], xb[n * 3 + 1], xb[n * 3 + 2],
                   cx, cy, cz, r0, r1, r2, r3, r4, r5, r6, r7, r8);
}

// Selection for one query -> writes 64 indices to s_out (LDS).
// Branch choice is block-uniform (v in LDS); barriers OK. No early returns.
__device__ void select_idx(QS& qs, const float* __restrict__ xb,
                           float cx, float cy, float cz,
                           float r0, float r1, float r2, float r3, float r4,
                           float r5, float r6, float r7, float r8,
                           int* s_out) {
    const int tid = threadIdx.x;
    const int wid = tid >> 6;
    const int v = qs.cnt;

    if (v == 0) {
        // rare: no point in cylinder -> every slot = argmin d2 (first occurrence)
        u64 fb = ~0ull;
        for (int n = tid; n < N_; n += 256) {
            float px = xb[n * 3 + 0], py = xb[n * 3 + 1], pz = xb[n * 3 + 2];
            float dx = px - cx, dy = py - cy, dz = pz - cz;
            float d2 = __fadd_rn(__fadd_rn(__fmul_rn(dx, dx), __fmul_rn(dy, dy)),
                                 __fmul_rn(dz, dz));
            fb = umin64(fb, ((u64)__float_as_uint(d2) << 32) | (unsigned)n);
        }
        u64 m = block_min_u64(fb, qs.red);
        if (tid < S_) s_out[tid] = (int)(unsigned)(m & 0xFFFFFFFFu);
    } else if (v <= 64) {
        // pad to 64 with unique huge keys (real idx < 0x4000, pads >= 0x10000)
        if (tid >= v && tid < 64)
            qs.keys[tid] = 0xFFFFFFFF00000000ull | (unsigned)(0x10000 + tid);
        __syncthreads();
        u64 key = 0;
        int rank = 0;
        if (tid < 64) {
            key = qs.keys[tid];
            for (int o = 0; o < 64; ++o) rank += (qs.keys[o] < key) ? 1 : 0;
        }
        __syncthreads();
        if (tid < 64) qs.keys[rank] = key;
        __syncthreads();
        // fill remaining slots with smallest-index invalid points (ascending).
        // v <= 63 when needed>0, so n in [0,128) holds >= 65 invalid points.
        const int needed = 64 - v;
        if (tid < 64 && needed > 0) {
            bool inv0 = (qs.vflag[tid] == 0);
            u64 m0 = __ballot(inv0);
            int before0 = __popcll(m0 & ((1ull << tid) - 1ull));
            if (inv0 && before0 < needed) qs.keys[v + before0] = (unsigned)tid;
            int c0 = __popcll(m0);
            if (c0 < needed) {
                bool inv1 = (qs.vflag[64 + tid] == 0);
                u64 m1 = __ballot(inv1);
                int b1 = c0 + __popcll(m1 & ((1ull << tid) - 1ull));
                if (inv1 && b1 < needed) qs.keys[v + b1] = (unsigned)(64 + tid);
            }
        }
        __syncthreads();
        if (tid < S_) s_out[tid] = (int)(unsigned)(qs.keys[tid] & 0xFFFFFFFFu);
    } else if (v <= CAP_) {
        // all valid keys already compacted; rank-sort, emit ranks < 64
        for (int i = tid; i < v; i += 256) {
            u64 key = qs.keys[i];
            int rank = 0;
            for (int j = 0; j < v; ++j) rank += (qs.keys[j] < key) ? 1 : 0;
            if (rank < 64) s_out[rank] = (int)(unsigned)(key & 0xFFFFFFFFu);
        }
    } else {
        // rare: v > CAP_. 4-pass radix select of 64th-smallest score (recompute).
        uint32_t prefix = 0, mask = 0, kk = 64;
        for (int pass = 0; pass < 4; ++pass) {
            const int shift = 24 - 8 * pass;
            __syncthreads();
            qs.hist[0][tid] = 0;
            qs.hist[1][tid] = 0;
            qs.hist[2][tid] = 0;
            qs.hist[3][tid] = 0;
            __syncthreads();
            for (int n = tid; n < N_; n += 256) {
                uint32_t sb = score_bits(xb, n, cx, cy, cz, r0, r1, r2, r3, r4, r5, r6, r7, r8);
                if (sb != INF_BITS && (sb & mask) == prefix)
                    atomicAdd(&qs.hist[wid][(sb >> shift) & 255u], 1u);
            }
            __syncthreads();
            uint32_t cnt = qs.hist[0][tid] + qs.hist[1][tid] + qs.hist[2][tid] + qs.hist[3][tid];
            uint32_t x = cnt;
#pragma unroll
            for (int o = 1; o < 64; o <<= 1) {
                uint32_t y = __shfl_up(x, o, 64);
                if ((tid & 63) >= o) x += y;
            }
            if ((tid & 63) == 63) qs.wsum[wid] = x;
            __syncthreads();
            uint32_t woff = 0;
            for (int w = 0; w < wid; ++w) woff += qs.wsum[w];
            uint32_t incl = x + woff;
            uint32_t excl = incl - cnt;
            if (kk > excl && kk <= incl) {  // exactly one thread
                qs.sel = tid;
                qs.k = kk - excl;
            }
            __syncthreads();
            prefix |= ((uint32_t)qs.sel) << shift;
            mask |= 255u << shift;
            kk = qs.k;
        }
        const uint32_t T = prefix;  // exact 64th-smallest score bits

        __syncthreads();
        if (tid == 0) qs.cnt = 0;
        __syncthreads();
        for (int n = tid; n < N_; n += 256) {
            uint32_t sb = score_bits(xb, n, cx, cy, cz, r0, r1, r2, r3, r4, r5, r6, r7, r8);
            if (sb != INF_BITS && sb <= T) {
                int pos = atomicAdd(&qs.cnt, 1);
                if (pos < CAP_) qs.keys[pos] = ((u64)sb << 32) | (unsigned)n;
            }
        }
        __syncthreads();
        int c = qs.cnt;
        if (c > CAP_) c = CAP_;  // unreachable without >448 exact float ties
        for (int i = tid; i < c; i += 256) {
            u64 key = qs.keys[i];
            int rank = 0;
            for (int j = 0; j < c; ++j) rank += (qs.keys[j] < key) ? 1 : 0;
            if (rank < 64) s_out[rank] = (int)(unsigned)(key & 0xFFFFFFFFu);
        }
    }
}

// ---------------- feature transpose: (B,C,N) fp32 -> (B,N,C) bf16 ----------------
__global__ __launch_bounds__(256) void transpose_kernel(const float* __restrict__ feat,
                                                        ushort* __restrict__ featT) {
    int t = blockIdx.x;
    int b = t >> 10;
    int rem = t & 1023;
    int cblk = rem >> 8;   // 0..3
    int nblk = rem & 255;  // 0..255
    __shared__ float tile[64][65];
    int tid = threadIdx.x;
    for (int i = tid; i < 64 * 64; i += 256) {
        int cy = i >> 6, nx = i & 63;
        tile[cy][nx] = feat[((size_t)(b * C_ + cblk * 64 + cy)) * N_ + nblk * 64 + nx];
    }
    __syncthreads();
    // write bf16 pairs: 64 rows (ny) x 32 channel-pairs
    for (int i = tid; i < 64 * 32; i += 256) {
        int ny = i >> 5, cp = i & 31;
        uint32_t u0 = f2bf(tile[2 * cp + 0][ny]);
        uint32_t u1 = f2bf(tile[2 * cp + 1][ny]);
        *(uint32_t*)&featT[((size_t)(b * N_ + nblk * 64 + ny)) * C_ + cblk * 64 + 2 * cp] =
            u0 | (u1 << 16);
    }
}

// ---------------- fused: cylinder query + group, one bp per block ----------------
__global__ __launch_bounds__(256) void qg_kernel(const ushort* __restrict__ featT,
                                                 const float* __restrict__ features,
                                                 const float* __restrict__ xyz,
                                                 const float* __restrict__ new_xyz,
                                                 const float* __restrict__ rot,
                                                 float* __restrict__ out, int useT) {
    __shared__ USmem sm;
    __shared__ int s_idx[S_];
    const int tid = threadIdx.x;
    const int lane = tid & 63;
    const int bp = blockIdx.x;
    const int b = bp >> 10;
    const int p = bp & 1023;

    if (tid == 0) sm.qs.cnt = 0;

    const float cx = new_xyz[bp * 3 + 0];
    const float cy = new_xyz[bp * 3 + 1];
    const float cz = new_xyz[bp * 3 + 2];
    const float* R = rot + (size_t)bp * 9;
    const float r0 = R[0], r1 = R[1], r2 = R[2];
    const float r3 = R[3], r4 = R[4], r5 = R[5];
    const float r6 = R[6], r7 = R[7], r8 = R[8];

    __syncthreads();  // cnt initialized

    const float* xb = xyz + (size_t)b * N_ * 3;
    const float4* xb4 = (const float4*)xb;

    // ---- query main pass: 4 points/thread/iter via 3x dwordx4 ----
    for (int it = 0; it < N_ / 1024; ++it) {
        int t4 = it * 256 + tid;
        float4 A = xb4[t4 * 3 + 0];
        float4 Bv = xb4[t4 * 3 + 1];
        float4 Cv = xb4[t4 * 3 + 2];
        int n0 = t4 * 4;

        uint32_t s0 = eval_sb(A.x, A.y, A.z, cx, cy, cz, r0, r1, r2, r3, r4, r5, r6, r7, r8);
        uint32_t s1 = eval_sb(A.w, Bv.x, Bv.y, cx, cy, cz, r0, r1, r2, r3, r4, r5, r6, r7, r8);
        uint32_t s2 = eval_sb(Bv.z, Bv.w, Cv.x, cx, cy, cz, r0, r1, r2, r3, r4, r5, r6, r7, r8);
        uint32_t s3 = eval_sb(Cv.y, Cv.z, Cv.w, cx, cy, cz, r0, r1, r2, r3, r4, r5, r6, r7, r8);

        if (it == 0 && tid < 32) {
            sm.qs.vflag[n0 + 0] = (s0 != INF_BITS) ? 1 : 0;
            sm.qs.vflag[n0 + 1] = (s1 != INF_BITS) ? 1 : 0;
            sm.qs.vflag[n0 + 2] = (s2 != INF_BITS) ? 1 : 0;
            sm.qs.vflag[n0 + 3] = (s3 != INF_BITS) ? 1 : 0;
        }
        uint32_t mn = min(min(s0, s1), min(s2, s3));
        if (__any(mn != INF_BITS)) {
            uint32_t sb[4] = {s0, s1, s2, s3};
#pragma unroll
            for (int j = 0; j < 4; ++j) {
                u64 m = __ballot(sb[j] != INF_BITS);
                if (m) {  // wave-uniform
                    int leader = __builtin_ctzll(m);
                    int cnt = __popcll(m);
                    int base = 0;
                    if (lane == leader) base = atomicAdd(&sm.qs.cnt, cnt);
                    base = __shfl(base, leader, 64);
                    if (sb[j] != INF_BITS) {
                        int pos = base + __popcll(m & ((1ull << lane) - 1ull));
                        if (pos < CAP_) sm.qs.keys[pos] = ((u64)sb[j] << 32) | (unsigned)(n0 + j);
                    }
                }
            }
        }
    }
    __syncthreads();

    // ---- selection -> s_idx (LDS) ----
    select_idx(sm.qs, xb, cx, cy, cz, r0, r1, r2, r3, r4, r5, r6, r7, r8, s_idx);
    __syncthreads();  // s_idx visible; qs no longer read (tile may overwrite union)

    // ---- group: xyz part (3 channels) ----
    if (tid < S_) {
        int n = s_idx[tid];
        const float* pt = xyz + ((size_t)b * N_ + n) * 3;
        float dx = pt[0] - cx;
        float dy = pt[1] - cy;
        float dz = pt[2] - cz;
        // g_e = ((dx*R[0,e] + dy*R[1,e]) + dz*R[2,e]), no FMA
        float g0 = __fadd_rn(__fadd_rn(__fmul_rn(dx, r0), __fmul_rn(dy, r3)), __fmul_rn(dz, r6));
        float g1 = __fadd_rn(__fadd_rn(__fmul_rn(dx, r1), __fmul_rn(dy, r4)), __fmul_rn(dz, r7));
        float g2 = __fadd_rn(__fadd_rn(__fmul_rn(dx, r2), __fmul_rn(dy, r5)), __fmul_rn(dz, r8));
        out[(((size_t)b * CH_ + 0) * P_ + p) * S_ + tid] = g0;
        out[(((size_t)b * CH_ + 1) * P_ + p) * S_ + tid] = g1;
        out[(((size_t)b * CH_ + 2) * P_ + p) * S_ + tid] = g2;
    }

    // ---- group: features, two s-halves of 32 samples each ----
    for (int h = 0; h < 2; ++h) {
        if (h) __syncthreads();  // protect tile reuse
        // Phase A: gather 32 bf16 rows into tileu[sl][cp] (sample-major)
        if (useT) {
            // uint2 per lane (4 channel-pairs); one 512B row per wave-iter; b64 LDS
            // writes at consecutive addresses -> conflict-free.
            for (int i = tid; i < 32 * 64; i += 256) {
                int sl = i >> 6, cd = i & 63;
                int n = s_idx[h * 32 + sl];
                uint2 v = *(const uint2*)&featT[((size_t)b * N_ + n) * C_ + cd * 4];
                *(uint2*)&sm.g.tileu[sl][cd * 2] = v;
            }
        } else {
            // fallback (no workspace): scalar gathers from (C,N), pack to bf16
            for (int i = tid; i < 32 * 128; i += 256) {
                int sl = i >> 7, cp = i & 127;
                int n = s_idx[h * 32 + sl];
                uint32_t u0 = f2bf(features[((size_t)b * C_ + 2 * cp + 0) * N_ + n]);
                uint32_t u1 = f2bf(features[((size_t)b * C_ + 2 * cp + 1) * N_ + n]);
                sm.g.tileu[sl][cp] = u0 | (u1 << 16);
            }
        }
        __syncthreads();
        // Phase B: each thread reads 4 uints (2-way LDS, free) and emits TWO float4
        // stores (c=2cp, 2cp+1); 8 q-lanes per c -> 128B contiguous lines.
        for (int i = tid; i < (C_ / 2) * 8; i += 256) {
            int cp = i >> 3, q = i & 7;
            uint32_t u0 = sm.g.tileu[4 * q + 0][cp];
            uint32_t u1 = sm.g.tileu[4 * q + 1][cp];
            uint32_t u2 = sm.g.tileu[4 * q + 2][cp];
            uint32_t u3 = sm.g.tileu[4 * q + 3][cp];
            float4 lo, hi;
            lo.x = bf2f(u0 & 0xffffu); lo.y = bf2f(u1 & 0xffffu);
            lo.z = bf2f(u2 & 0xffffu); lo.w = bf2f(u3 & 0xffffu);
            hi.x = bf2f(u0 >> 16); hi.y = bf2f(u1 >> 16);
            hi.z = bf2f(u2 >> 16); hi.w = bf2f(u3 >> 16);
            size_t base0 = (((size_t)b * CH_ + 3 + 2 * cp) * P_ + p) * S_ + h * 32 + 4 * q;
            *(float4*)&out[base0] = lo;
            *(float4*)&out[base0 + (size_t)P_ * S_] = hi;
        }
    }
}

extern "C" void kernel_launch(void* const* d_in, const int* in_sizes, int n_in,
                              void* d_out, int out_size, void* d_ws, size_t ws_size,
                              hipStream_t stream) {
    const float* xyz = (const float*)d_in[0];       // (B,N,3)
    const float* new_xyz = (const float*)d_in[1];   // (B,P,3)
    const float* rot = (const float*)d_in[2];       // (B,P,3,3)
    const float* features = (const float*)d_in[3];  // (B,C,N)
    float* out = (float*)d_out;

    const size_t featT_bytes = (size_t)B_ * N_ * C_ * sizeof(ushort);  // 16.8 MB
    const int useT = (ws_size >= featT_bytes) ? 1 : 0;

    ushort* featT = (ushort*)d_ws;

    if (useT) {
        transpose_kernel<<<2048, 256, 0, stream>>>(features, featT);
    }
    qg_kernel<<<B_ * P_, 256, 0, stream>>>(featT, features, xyz, new_xyz, rot, out, useT);
}